// Round 2
// baseline (1866.898 us; speedup 1.0000x reference)
//
#include <hip/hip_runtime.h>
#include <math.h>

#define BB 128
#define NTOK 197
#define CC 768
#define HH 12
#define HD 64
#define HIDN 3072
#define NP 177
#define NPATCH 196
#define THRK 19
#define MR (BB*NP)   // 22656 rows

using short8 = __attribute__((ext_vector_type(8))) short;
using f32x4  = __attribute__((ext_vector_type(4))) float;

__device__ __forceinline__ unsigned short f2b(float f){
  unsigned u = __builtin_bit_cast(unsigned, f);
  u += 0x7fffu + ((u >> 16) & 1u);
  return (unsigned short)(u >> 16);
}

// ---------- weight fp32 -> bf16 ----------
__global__ void cvt_kernel(const float* __restrict__ in, unsigned short* __restrict__ out, int n){
  int i = blockIdx.x * 256 + threadIdx.x;
  if (i < n) out[i] = f2b(in[i]);
}

// ---------- scoring path (fp64 accum: selection boundary must not flip) ----------
__global__ void q0_kernel(const float* __restrict__ x, const float* __restrict__ Wqkv, float* __restrict__ q0){
  int b = blockIdx.x, t = threadIdx.x;
  __shared__ float xs[CC];
  for (int c = t; c < CC; c += 256) xs[c] = x[(size_t)b*NTOK*CC + c];
  __syncthreads();
  for (int c = t; c < CC; c += 256){
    double acc = 0.0;
    for (int j = 0; j < CC; ++j) acc = fma((double)xs[j], (double)Wqkv[(size_t)j*(3*CC) + c], acc);
    q0[b*CC + c] = (float)acc;
  }
}

__global__ void wvec_kernel(const float* __restrict__ Wqkv, const float* __restrict__ q0, float* __restrict__ wv){
  int b = blockIdx.x, t = threadIdx.x;
  __shared__ float qs[CC];
  for (int c = t; c < CC; c += 256) qs[c] = q0[b*CC + c];
  __syncthreads();
  for (int j = t; j < CC; j += 256){
    const float* row = Wqkv + (size_t)j*(3*CC) + CC;  // Wk column block
    double acc = 0.0;
    for (int c = 0; c < CC; ++c) acc = fma((double)row[c], (double)qs[c], acc);
    wv[b*CC + j] = (float)acc;
  }
}

__global__ void score_kernel(const float* __restrict__ x, const float* __restrict__ wv, float* __restrict__ sc){
  int m = blockIdx.x, b = blockIdx.y, l = threadIdx.x;  // one wave per (b,m)
  const float* xr = x + ((size_t)b*NTOK + 1 + m)*CC;
  const float* wr = wv + b*CC;
  double acc = 0.0;
  for (int c = l; c < CC; c += 64) acc = fma((double)xr[c], (double)wr[c], acc);
  for (int off = 32; off; off >>= 1) acc += __shfl_down(acc, off);
  if (l == 0) sc[b*NPATCH + m] = (float)(acc * (1.0/12.0));
}

// stable rank (== argsort(argsort) with stable ties), keep rank>19, compact in order
__global__ void select_kernel(const float* __restrict__ sc, int* __restrict__ tok){
  int b = blockIdx.x, t = threadIdx.x;
  __shared__ float s[NPATCH];
  __shared__ int kp[NPATCH];
  for (int m = t; m < NPATCH; m += 256) s[m] = sc[b*NPATCH + m];
  __syncthreads();
  for (int m = t; m < NPATCH; m += 256){
    float v = s[m]; int rank = 0;
    for (int j = 0; j < NPATCH; ++j){
      float u = s[j];
      rank += (u < v) || (u == v && j < m);
    }
    kp[m] = (rank > THRK) ? 1 : 0;
  }
  __syncthreads();
  for (int m = t; m < NPATCH; m += 256){
    if (kp[m]){
      int pos = 0;
      for (int j = 0; j < m; ++j) pos += kp[j];
      tok[b*NP + 1 + pos] = m + 1;
    }
  }
  if (t == 0) tok[b*NP] = 0;
}

__global__ void gather_kernel(const float* __restrict__ x, const int* __restrict__ tok, float* __restrict__ xk){
  int i = blockIdx.x, b = blockIdx.y, t = threadIdx.x;
  int src = tok[b*NP + i];
  const float* xr = x + ((size_t)b*NTOK + src)*CC;
  float* o = xk + ((size_t)b*NP + i)*CC;
  for (int c = t; c < CC; c += 256) o[c] = xr[c] * (1.0f/0.9f);
}

// ---------- LayerNorm: fp32 in -> bf16 out ----------
__global__ void ln_kernel(const float* __restrict__ in, const float* __restrict__ g,
                          const float* __restrict__ bt, unsigned short* __restrict__ out){
  int row = blockIdx.x, t = threadIdx.x;
  const float* xr = in + (size_t)row*CC;
  float v0 = xr[t], v1 = xr[t+256], v2 = xr[t+512];
  float s = v0+v1+v2, ss = v0*v0+v1*v1+v2*v2;
  for (int off = 32; off; off >>= 1){ s += __shfl_down(s, off); ss += __shfl_down(ss, off); }
  __shared__ float red[8];
  int wid = t >> 6, lane = t & 63;
  if (lane == 0){ red[wid] = s; red[4+wid] = ss; }
  __syncthreads();
  if (t == 0){
    float S = red[0]+red[1]+red[2]+red[3], SS = red[4]+red[5]+red[6]+red[7];
    float mean = S * (1.0f/CC);
    float var = SS * (1.0f/CC) - mean*mean;
    red[0] = mean; red[1] = rsqrtf(var + 1e-5f);
  }
  __syncthreads();
  float mean = red[0], rstd = red[1];
  unsigned short* orow = out + (size_t)row*CC;
  orow[t]     = f2b((v0-mean)*rstd*g[t]     + bt[t]);
  orow[t+256] = f2b((v1-mean)*rstd*g[t+256] + bt[t+256]);
  orow[t+512] = f2b((v2-mean)*rstd*g[t+512] + bt[t+512]);
}

// ---------- generic bf16 MFMA GEMM, 64x64 tile, BK=32, 4 waves ----------
// EPI: 0 = plain -> bf16 out ; 1/3 = +bias +res -> f32 out ; 2 = +bias, gelu -> bf16 out
template<int EPI>
__global__ __launch_bounds__(256) void gemm64(
    const unsigned short* __restrict__ A, const unsigned short* __restrict__ Bw,
    const float* __restrict__ bias, const float* __restrict__ res, void* __restrict__ outp,
    int M, int N, int K)
{
  __shared__ short As[64*32];
  __shared__ short Bt[64*32];   // Bt[n][k]
  int m0 = blockIdx.y*64, n0 = blockIdx.x*64;
  int t = threadIdx.x;
  int w = t >> 6, l = t & 63;
  int wr = w >> 1, wc = w & 1;
  f32x4 acc[2][2] = {};
  int arow = t >> 2, ak0 = (t & 3)*8;
  int bk = t >> 3,  bn0 = (t & 7)*8;
  for (int kt = 0; kt < K; kt += 32){
    short8 av = *reinterpret_cast<const short8*>(A  + (size_t)(m0+arow)*K + kt + ak0);
    short8 bv = *reinterpret_cast<const short8*>(Bw + (size_t)(kt+bk)*N + n0 + bn0);
    *reinterpret_cast<short8*>(&As[arow*32 + ak0]) = av;
    #pragma unroll
    for (int j = 0; j < 8; ++j) Bt[(bn0+j)*32 + bk] = bv[j];
    __syncthreads();
    short8 a0 = *reinterpret_cast<const short8*>(&As[(wr*32      + (l&15))*32 + 8*(l>>4)]);
    short8 a1 = *reinterpret_cast<const short8*>(&As[(wr*32 + 16 + (l&15))*32 + 8*(l>>4)]);
    short8 b0 = *reinterpret_cast<const short8*>(&Bt[(wc*32      + (l&15))*32 + 8*(l>>4)]);
    short8 b1 = *reinterpret_cast<const short8*>(&Bt[(wc*32 + 16 + (l&15))*32 + 8*(l>>4)]);
    acc[0][0] = __builtin_amdgcn_mfma_f32_16x16x32_bf16(a0, b0, acc[0][0], 0, 0, 0);
    acc[0][1] = __builtin_amdgcn_mfma_f32_16x16x32_bf16(a0, b1, acc[0][1], 0, 0, 0);
    acc[1][0] = __builtin_amdgcn_mfma_f32_16x16x32_bf16(a1, b0, acc[1][0], 0, 0, 0);
    acc[1][1] = __builtin_amdgcn_mfma_f32_16x16x32_bf16(a1, b1, acc[1][1], 0, 0, 0);
    __syncthreads();
  }
  #pragma unroll
  for (int fi = 0; fi < 2; ++fi)
  #pragma unroll
  for (int fj = 0; fj < 2; ++fj){
    int row = m0 + wr*32 + fi*16 + 4*(l>>4);
    int col = n0 + wc*32 + fj*16 + (l&15);
    #pragma unroll
    for (int r = 0; r < 4; ++r){
      float v = acc[fi][fj][r];
      if (EPI != 0) v += bias[col];
      if (EPI == 2) v = 0.5f*v*(1.0f + erff(v*0.70710678118f));
      if (EPI == 1 || EPI == 3) v += res[(size_t)(row+r)*N + col];
      if (EPI == 0 || EPI == 2) ((unsigned short*)outp)[(size_t)(row+r)*N + col] = f2b(v);
      else                      ((float*)outp)[(size_t)(row+r)*N + col] = v;
    }
  }
}

// ---------- fused attention: QK^T -> softmax -> PV, per (rowblock, head, batch) ----------
__global__ __launch_bounds__(256) void attn_kernel(const unsigned short* __restrict__ qkv2,
                                                   unsigned short* __restrict__ o)
{
  int rt = blockIdx.x, h = blockIdx.y, b = blockIdx.z;
  int t = threadIdx.x, w = t >> 6, l = t & 63;
  __shared__ short Vt[64*192];       // Vt[d][m], m padded to 192
  __shared__ short P[4][16*192];     // per-wave P strip
  // stage V transposed
  for (int idx = t; idx < NP*8; idx += 256){
    int m = idx >> 3, d0 = (idx & 7)*8;
    short8 v = *reinterpret_cast<const short8*>(qkv2 + (size_t)(b*NP+m)*(3*CC) + 2*CC + h*HD + d0);
    #pragma unroll
    for (int j = 0; j < 8; ++j) Vt[(d0+j)*192 + m] = v[j];
  }
  for (int idx = t; idx < 64*15; idx += 256){
    int d = idx/15, m = NP + idx%15;
    Vt[d*192 + m] = 0;
  }
  __syncthreads();
  int nb = rt*64 + w*16;
  int g = l >> 4, c = l & 15;
  int nq = nb + c; if (nq > NP-1) nq = NP-1;
  const unsigned short* qrow = qkv2 + (size_t)(b*NP+nq)*(3*CC) + h*HD + 8*g;
  short8 aq0 = *reinterpret_cast<const short8*>(qrow);
  short8 aq1 = *reinterpret_cast<const short8*>(qrow + 32);
  f32x4 acc[12];
  #pragma unroll
  for (int ct = 0; ct < 12; ++ct){
    int m = ct*16 + c; if (m > NP-1) m = NP-1;
    const unsigned short* krow = qkv2 + (size_t)(b*NP+m)*(3*CC) + CC + h*HD + 8*g;
    short8 bk0 = *reinterpret_cast<const short8*>(krow);
    short8 bk1 = *reinterpret_cast<const short8*>(krow + 32);
    f32x4 a = {};
    a = __builtin_amdgcn_mfma_f32_16x16x32_bf16(aq0, bk0, a, 0, 0, 0);
    a = __builtin_amdgcn_mfma_f32_16x16x32_bf16(aq1, bk1, a, 0, 0, 0);
    acc[ct] = a;
  }
  float mx[4] = {-INFINITY, -INFINITY, -INFINITY, -INFINITY};
  #pragma unroll
  for (int ct = 0; ct < 12; ++ct){
    bool valid = (ct*16 + c) < NP;
    #pragma unroll
    for (int r = 0; r < 4; ++r){
      float v = valid ? acc[ct][r]*0.125f : -INFINITY;
      acc[ct][r] = v;
      mx[r] = fmaxf(mx[r], v);
    }
  }
  #pragma unroll
  for (int off = 1; off < 16; off <<= 1){
    #pragma unroll
    for (int r = 0; r < 4; ++r) mx[r] = fmaxf(mx[r], __shfl_xor(mx[r], off));
  }
  float sm[4] = {0.f, 0.f, 0.f, 0.f};
  #pragma unroll
  for (int ct = 0; ct < 12; ++ct)
    #pragma unroll
    for (int r = 0; r < 4; ++r){
      float e = __expf(acc[ct][r] - mx[r]);   // exp(-inf)=0 masks invalid cols
      acc[ct][r] = e; sm[r] += e;
    }
  #pragma unroll
  for (int off = 1; off < 16; off <<= 1){
    #pragma unroll
    for (int r = 0; r < 4; ++r) sm[r] += __shfl_xor(sm[r], off);
  }
  float inv[4];
  #pragma unroll
  for (int r = 0; r < 4; ++r) inv[r] = 1.0f / sm[r];
  #pragma unroll
  for (int ct = 0; ct < 12; ++ct)
    #pragma unroll
    for (int r = 0; r < 4; ++r)
      P[w][(4*g + r)*192 + ct*16 + c] = (short)f2b(acc[ct][r]*inv[r]);
  f32x4 acc2[4] = {};
  #pragma unroll
  for (int ks = 0; ks < 6; ++ks){
    short8 pa = *reinterpret_cast<const short8*>(&P[w][c*192 + ks*32 + 8*g]);
    #pragma unroll
    for (int ct2 = 0; ct2 < 4; ++ct2){
      short8 bv = *reinterpret_cast<const short8*>(&Vt[(ct2*16 + c)*192 + ks*32 + 8*g]);
      acc2[ct2] = __builtin_amdgcn_mfma_f32_16x16x32_bf16(pa, bv, acc2[ct2], 0, 0, 0);
    }
  }
  #pragma unroll
  for (int ct2 = 0; ct2 < 4; ++ct2){
    #pragma unroll
    for (int r = 0; r < 4; ++r){
      int n = nb + 4*g + r;
      if (n < NP) o[(size_t)(b*NP+n)*CC + h*HD + ct2*16 + c] = f2b(acc2[ct2][r]);
    }
  }
}

extern "C" void kernel_launch(void* const* d_in, const int* in_sizes, int n_in,
                              void* d_out, int out_size, void* d_ws, size_t ws_size,
                              hipStream_t stream) {
  const float* x     = (const float*)d_in[0];
  const float* ln1g  = (const float*)d_in[1];
  const float* ln1b  = (const float*)d_in[2];
  const float* Wqkv  = (const float*)d_in[3];
  const float* Wproj = (const float*)d_in[4];
  const float* bproj = (const float*)d_in[5];
  const float* ln2g  = (const float*)d_in[6];
  const float* ln2b  = (const float*)d_in[7];
  const float* W1    = (const float*)d_in[8];
  const float* b1    = (const float*)d_in[9];
  const float* W2    = (const float*)d_in[10];
  const float* b2    = (const float*)d_in[11];
  float* out = (float*)d_out;

  unsigned char* base = (unsigned char*)d_ws;
  size_t off = 0;
  auto alloc = [&](size_t bytes) -> void* {
    off = (off + 255) & ~(size_t)255;
    void* p = base + off;
    off += bytes;
    return p;
  };
  // Aliased workspace layout (lifetimes checked): total ~224 MB
  unsigned short* Wqkv_h  = (unsigned short*)alloc((size_t)CC*3*CC*2);
  unsigned short* Wproj_h = (unsigned short*)alloc((size_t)CC*CC*2);
  unsigned short* W1_h    = (unsigned short*)alloc((size_t)CC*HIDN*2);
  unsigned short* W2_h    = (unsigned short*)alloc((size_t)HIDN*CC*2);
  float* q0   = (float*)alloc((size_t)BB*CC*4);
  float* wv   = (float*)alloc((size_t)BB*CC*4);
  float* sc   = (float*)alloc((size_t)BB*NPATCH*4);
  int*   tok  = (int*)alloc((size_t)BB*NP*4);
  unsigned short* hbuf = (unsigned short*)alloc((size_t)MR*CC*2);   // ln1-out, then attn-out, then ln2-out
  float* xk   = (float*)alloc((size_t)MR*CC*4);                     // dead after proj-GEMM
  unsigned short* qkv2 = (unsigned short*)alloc((size_t)MR*3*CC*2); // dead after attention
  if (off > ws_size) return;  // clean fail (no fault) if workspace too small

  unsigned short* obuf = hbuf;                 // alias: ln1-out dead when attn writes
  unsigned short* mid  = (unsigned short*)xk;  // alias: xk+qkv2 region (174 MB >= 139.2 MB)
  float* x2 = out;                             // residual stream 2 lives in d_out

  { int n = CC*3*CC;  cvt_kernel<<<(n+255)/256, 256, 0, stream>>>(Wqkv, Wqkv_h, n); }
  { int n = CC*CC;    cvt_kernel<<<(n+255)/256, 256, 0, stream>>>(Wproj, Wproj_h, n); }
  { int n = CC*HIDN;  cvt_kernel<<<(n+255)/256, 256, 0, stream>>>(W1, W1_h, n); }
  { int n = HIDN*CC;  cvt_kernel<<<(n+255)/256, 256, 0, stream>>>(W2, W2_h, n); }

  // scoring + selection + gather
  q0_kernel<<<BB, 256, 0, stream>>>(x, Wqkv, q0);
  wvec_kernel<<<BB, 256, 0, stream>>>(Wqkv, q0, wv);
  score_kernel<<<dim3(NPATCH, BB), 64, 0, stream>>>(x, wv, sc);
  select_kernel<<<BB, 256, 0, stream>>>(sc, tok);
  gather_kernel<<<dim3(NP, BB), 256, 0, stream>>>(x, tok, xk);

  // attention block
  ln_kernel<<<MR, 256, 0, stream>>>(xk, ln1g, ln1b, hbuf);
  gemm64<0><<<dim3((3*CC)/64, MR/64), 256, 0, stream>>>(hbuf, Wqkv_h, nullptr, nullptr, qkv2, MR, 3*CC, CC);
  attn_kernel<<<dim3(3, HH, BB), 256, 0, stream>>>(qkv2, obuf);
  gemm64<1><<<dim3(CC/64, MR/64), 256, 0, stream>>>(obuf, Wproj_h, bproj, xk, x2, MR, CC, CC);

  // MLP block
  ln_kernel<<<MR, 256, 0, stream>>>(x2, ln2g, ln2b, hbuf);
  gemm64<2><<<dim3(HIDN/64, MR/64), 256, 0, stream>>>(hbuf, W1_h, b1, nullptr, mid, MR, HIDN, CC);
  gemm64<3><<<dim3(CC/64, MR/64), 256, 0, stream>>>(mid, W2_h, b2, x2, out, MR, CC, HIDN);
}

// Round 3
// 1034.020 us; speedup vs baseline: 1.8055x; 1.8055x over previous
//
#include <hip/hip_runtime.h>
#include <math.h>

#define BB 128
#define NTOK 197
#define CC 768
#define HH 12
#define HD 64
#define HIDN 3072
#define NP 177
#define NPATCH 196
#define THRK 19
#define MR (BB*NP)   // 22656 rows = 177*128

using short8 = __attribute__((ext_vector_type(8))) short;
using f32x4  = __attribute__((ext_vector_type(4))) float;

__device__ __forceinline__ unsigned short f2b(float f){
  unsigned u = __builtin_bit_cast(unsigned, f);
  u += 0x7fffu + ((u >> 16) & 1u);
  return (unsigned short)(u >> 16);
}

__device__ __forceinline__ void gload16(const void* src, void* lds){
  __builtin_amdgcn_global_load_lds(
      (const __attribute__((address_space(1))) unsigned int*)src,
      (__attribute__((address_space(3))) unsigned int*)lds,
      16, 0, 0);
}

// ---------- fused transpose+cvt: W[K][N] f32 -> Wt[N][K] bf16 ----------
__global__ void tcvt_kernel(const float* __restrict__ in, unsigned short* __restrict__ out, int K, int N){
  __shared__ float tile[64][65];
  int n0 = blockIdx.x*64, k0 = blockIdx.y*64;
  int t = threadIdx.x;
  int r = t >> 6, c = t & 63;
  #pragma unroll
  for (int i = 0; i < 16; ++i)
    tile[r + i*4][c] = in[(size_t)(k0 + r + i*4)*N + n0 + c];
  __syncthreads();
  #pragma unroll
  for (int i = 0; i < 16; ++i)
    out[(size_t)(n0 + r + i*4)*K + k0 + c] = f2b(tile[c][r + i*4]);
}

// ---------- scoring path (fp64 accum: selection boundary must not flip) ----------
__global__ void q0_kernel(const float* __restrict__ x, const float* __restrict__ Wqkv, float* __restrict__ q0){
  int b = blockIdx.x, t = threadIdx.x;
  __shared__ float xs[CC];
  for (int c = t; c < CC; c += 256) xs[c] = x[(size_t)b*NTOK*CC + c];
  __syncthreads();
  for (int c = t; c < CC; c += 256){
    double acc = 0.0;
    for (int j = 0; j < CC; ++j) acc = fma((double)xs[j], (double)Wqkv[(size_t)j*(3*CC) + c], acc);
    q0[b*CC + c] = (float)acc;
  }
}

__global__ void wvec_kernel(const float* __restrict__ Wqkv, const float* __restrict__ q0, float* __restrict__ wv){
  int b = blockIdx.x, t = threadIdx.x;
  __shared__ float qs[CC];
  for (int c = t; c < CC; c += 256) qs[c] = q0[b*CC + c];
  __syncthreads();
  for (int j = t; j < CC; j += 256){
    const float* row = Wqkv + (size_t)j*(3*CC) + CC;  // Wk column block
    double acc = 0.0;
    for (int c = 0; c < CC; ++c) acc = fma((double)row[c], (double)qs[c], acc);
    wv[b*CC + j] = (float)acc;
  }
}

__global__ void score_kernel(const float* __restrict__ x, const float* __restrict__ wv, float* __restrict__ sc){
  int m = blockIdx.x, b = blockIdx.y, l = threadIdx.x;  // one wave per (b,m)
  const float* xr = x + ((size_t)b*NTOK + 1 + m)*CC;
  const float* wr = wv + b*CC;
  double acc = 0.0;
  for (int c = l; c < CC; c += 64) acc = fma((double)xr[c], (double)wr[c], acc);
  for (int off = 32; off; off >>= 1) acc += __shfl_down(acc, off);
  if (l == 0) sc[b*NPATCH + m] = (float)(acc * (1.0/12.0));
}

// stable rank (== argsort(argsort) with stable ties), keep rank>19, compact in order
__global__ void select_kernel(const float* __restrict__ sc, int* __restrict__ tok){
  int b = blockIdx.x, t = threadIdx.x;
  __shared__ float s[NPATCH];
  __shared__ int kp[NPATCH];
  for (int m = t; m < NPATCH; m += 256) s[m] = sc[b*NPATCH + m];
  __syncthreads();
  for (int m = t; m < NPATCH; m += 256){
    float v = s[m]; int rank = 0;
    for (int j = 0; j < NPATCH; ++j){
      float u = s[j];
      rank += (u < v) || (u == v && j < m);
    }
    kp[m] = (rank > THRK) ? 1 : 0;
  }
  __syncthreads();
  for (int m = t; m < NPATCH; m += 256){
    if (kp[m]){
      int pos = 0;
      for (int j = 0; j < m; ++j) pos += kp[j];
      tok[b*NP + 1 + pos] = m + 1;
    }
  }
  if (t == 0) tok[b*NP] = 0;
}

__global__ void gather_kernel(const float* __restrict__ x, const int* __restrict__ tok, float* __restrict__ xk){
  int i = blockIdx.x, b = blockIdx.y, t = threadIdx.x;
  int src = tok[b*NP + i];
  const float* xr = x + ((size_t)b*NTOK + src)*CC;
  float* o = xk + ((size_t)b*NP + i)*CC;
  for (int c = t; c < CC; c += 256) o[c] = xr[c] * (1.0f/0.9f);
}

// ---------- LayerNorm: fp32 in -> bf16 out ----------
__global__ void ln_kernel(const float* __restrict__ in, const float* __restrict__ g,
                          const float* __restrict__ bt, unsigned short* __restrict__ out){
  int row = blockIdx.x, t = threadIdx.x;
  const float* xr = in + (size_t)row*CC;
  float v0 = xr[t], v1 = xr[t+256], v2 = xr[t+512];
  float s = v0+v1+v2, ss = v0*v0+v1*v1+v2*v2;
  for (int off = 32; off; off >>= 1){ s += __shfl_down(s, off); ss += __shfl_down(ss, off); }
  __shared__ float red[8];
  int wid = t >> 6, lane = t & 63;
  if (lane == 0){ red[wid] = s; red[4+wid] = ss; }
  __syncthreads();
  if (t == 0){
    float S = red[0]+red[1]+red[2]+red[3], SS = red[4]+red[5]+red[6]+red[7];
    float mean = S * (1.0f/CC);
    float var = SS * (1.0f/CC) - mean*mean;
    red[0] = mean; red[1] = rsqrtf(var + 1e-5f);
  }
  __syncthreads();
  float mean = red[0], rstd = red[1];
  unsigned short* orow = out + (size_t)row*CC;
  orow[t]     = f2b((v0-mean)*rstd*g[t]     + bt[t]);
  orow[t+256] = f2b((v1-mean)*rstd*g[t+256] + bt[t+256]);
  orow[t+512] = f2b((v2-mean)*rstd*g[t+512] + bt[t+512]);
}

// ---------- m97-structure GEMM: 128x128 tile, BK=32, global_load_lds, B^T weights ----------
// A [M][K] bf16 row-major, Bt [N][K] bf16 row-major. M%128==0, N%128==0, K%32==0.
// EPI: 0 = plain -> bf16 ; 1/3 = +bias +res -> f32 ; 2 = +bias, gelu -> bf16
template<int EPI>
__global__ __launch_bounds__(256) void gemm128(
    const unsigned short* __restrict__ A, const unsigned short* __restrict__ Bt,
    const float* __restrict__ bias, const float* __restrict__ res, void* __restrict__ outp,
    int M, int N, int K)
{
  __shared__ __align__(16) short As[128*32];
  __shared__ __align__(16) short Bs[128*32];
  // bijective XCD swizzle (m204), then consecutive wg share the A-panel
  int nwg = gridDim.x, o = blockIdx.x;
  int q = nwg >> 3, rr = nwg & 7;
  int xcd = o & 7, seq = o >> 3;
  int wg = (xcd < rr) ? xcd*(q+1) + seq : rr*(q+1) + (xcd - rr)*q + seq;
  int nx = N >> 7;
  int m0 = (wg / nx) << 7, n0 = (wg % nx) << 7;

  int t = threadIdx.x, w = t >> 6, l = t & 63;
  int wr = w >> 1, wc = w & 1;
  // staging source offsets: lane l covers row +(l>>2), k-chunk (l&3)*8
  int srow = w*16 + (l >> 2);
  int sk8  = (l & 3)*8;
  f32x4 acc[4][4] = {};

  for (int kt = 0; kt < K; kt += 32){
    #pragma unroll
    for (int j = 0; j < 2; ++j){
      gload16(A  + (size_t)(m0 + j*64 + srow)*K + kt + sk8, &As[(j*64 + w*16)*32]);
      gload16(Bt + (size_t)(n0 + j*64 + srow)*K + kt + sk8, &Bs[(j*64 + w*16)*32]);
    }
    __syncthreads();
    short8 af[4], bf[4];
    #pragma unroll
    for (int i = 0; i < 4; ++i){
      af[i] = *reinterpret_cast<const short8*>(&As[(wr*64 + i*16 + (l&15))*32 + (l>>4)*8]);
      bf[i] = *reinterpret_cast<const short8*>(&Bs[(wc*64 + i*16 + (l&15))*32 + (l>>4)*8]);
    }
    #pragma unroll
    for (int i = 0; i < 4; ++i)
      #pragma unroll
      for (int jn = 0; jn < 4; ++jn)
        acc[i][jn] = __builtin_amdgcn_mfma_f32_16x16x32_bf16(af[i], bf[jn], acc[i][jn], 0, 0, 0);
    __syncthreads();
  }

  #pragma unroll
  for (int i = 0; i < 4; ++i)
  #pragma unroll
  for (int jn = 0; jn < 4; ++jn){
    int row = m0 + wr*64 + i*16 + (l>>4)*4;
    int col = n0 + wc*64 + jn*16 + (l&15);
    #pragma unroll
    for (int r = 0; r < 4; ++r){
      float v = acc[i][jn][r];
      if (EPI != 0) v += bias[col];
      if (EPI == 2) v = 0.5f*v*(1.0f + erff(v*0.70710678118f));
      if (EPI == 1 || EPI == 3) v += res[(size_t)(row+r)*N + col];
      if (EPI == 0 || EPI == 2) ((unsigned short*)outp)[(size_t)(row+r)*N + col] = f2b(v);
      else                      ((float*)outp)[(size_t)(row+r)*N + col] = v;
    }
  }
}

// ---------- fused attention: QK^T -> softmax -> PV, per (rowblock, head, batch) ----------
__global__ __launch_bounds__(256) void attn_kernel(const unsigned short* __restrict__ qkv2,
                                                   unsigned short* __restrict__ o)
{
  int rt = blockIdx.x, h = blockIdx.y, b = blockIdx.z;
  int t = threadIdx.x, w = t >> 6, l = t & 63;
  __shared__ short Vt[64*192];       // Vt[d][m], m padded to 192
  __shared__ short P[4][16*192];     // per-wave P strip
  for (int idx = t; idx < NP*8; idx += 256){
    int m = idx >> 3, d0 = (idx & 7)*8;
    short8 v = *reinterpret_cast<const short8*>(qkv2 + (size_t)(b*NP+m)*(3*CC) + 2*CC + h*HD + d0);
    #pragma unroll
    for (int j = 0; j < 8; ++j) Vt[(d0+j)*192 + m] = v[j];
  }
  for (int idx = t; idx < 64*15; idx += 256){
    int d = idx/15, m = NP + idx%15;
    Vt[d*192 + m] = 0;
  }
  __syncthreads();
  int nb = rt*64 + w*16;
  int g = l >> 4, c = l & 15;
  int nq = nb + c; if (nq > NP-1) nq = NP-1;
  const unsigned short* qrow = qkv2 + (size_t)(b*NP+nq)*(3*CC) + h*HD + 8*g;
  short8 aq0 = *reinterpret_cast<const short8*>(qrow);
  short8 aq1 = *reinterpret_cast<const short8*>(qrow + 32);
  f32x4 acc[12];
  #pragma unroll
  for (int ct = 0; ct < 12; ++ct){
    int m = ct*16 + c; if (m > NP-1) m = NP-1;
    const unsigned short* krow = qkv2 + (size_t)(b*NP+m)*(3*CC) + CC + h*HD + 8*g;
    short8 bk0 = *reinterpret_cast<const short8*>(krow);
    short8 bk1 = *reinterpret_cast<const short8*>(krow + 32);
    f32x4 a = {};
    a = __builtin_amdgcn_mfma_f32_16x16x32_bf16(aq0, bk0, a, 0, 0, 0);
    a = __builtin_amdgcn_mfma_f32_16x16x32_bf16(aq1, bk1, a, 0, 0, 0);
    acc[ct] = a;
  }
  float mx[4] = {-INFINITY, -INFINITY, -INFINITY, -INFINITY};
  #pragma unroll
  for (int ct = 0; ct < 12; ++ct){
    bool valid = (ct*16 + c) < NP;
    #pragma unroll
    for (int r = 0; r < 4; ++r){
      float v = valid ? acc[ct][r]*0.125f : -INFINITY;
      acc[ct][r] = v;
      mx[r] = fmaxf(mx[r], v);
    }
  }
  #pragma unroll
  for (int off = 1; off < 16; off <<= 1){
    #pragma unroll
    for (int r = 0; r < 4; ++r) mx[r] = fmaxf(mx[r], __shfl_xor(mx[r], off));
  }
  float sm[4] = {0.f, 0.f, 0.f, 0.f};
  #pragma unroll
  for (int ct = 0; ct < 12; ++ct)
    #pragma unroll
    for (int r = 0; r < 4; ++r){
      float e = __expf(acc[ct][r] - mx[r]);
      acc[ct][r] = e; sm[r] += e;
    }
  #pragma unroll
  for (int off = 1; off < 16; off <<= 1){
    #pragma unroll
    for (int r = 0; r < 4; ++r) sm[r] += __shfl_xor(sm[r], off);
  }
  float inv[4];
  #pragma unroll
  for (int r = 0; r < 4; ++r) inv[r] = 1.0f / sm[r];
  #pragma unroll
  for (int ct = 0; ct < 12; ++ct)
    #pragma unroll
    for (int r = 0; r < 4; ++r)
      P[w][(4*g + r)*192 + ct*16 + c] = (short)f2b(acc[ct][r]*inv[r]);
  f32x4 acc2[4] = {};
  #pragma unroll
  for (int ks = 0; ks < 6; ++ks){
    short8 pa = *reinterpret_cast<const short8*>(&P[w][c*192 + ks*32 + 8*g]);
    #pragma unroll
    for (int ct2 = 0; ct2 < 4; ++ct2){
      short8 bv = *reinterpret_cast<const short8*>(&Vt[(ct2*16 + c)*192 + ks*32 + 8*g]);
      acc2[ct2] = __builtin_amdgcn_mfma_f32_16x16x32_bf16(pa, bv, acc2[ct2], 0, 0, 0);
    }
  }
  #pragma unroll
  for (int ct2 = 0; ct2 < 4; ++ct2){
    #pragma unroll
    for (int r = 0; r < 4; ++r){
      int n = nb + 4*g + r;
      if (n < NP) o[(size_t)(b*NP+n)*CC + h*HD + ct2*16 + c] = f2b(acc2[ct2][r]);
    }
  }
}

extern "C" void kernel_launch(void* const* d_in, const int* in_sizes, int n_in,
                              void* d_out, int out_size, void* d_ws, size_t ws_size,
                              hipStream_t stream) {
  const float* x     = (const float*)d_in[0];
  const float* ln1g  = (const float*)d_in[1];
  const float* ln1b  = (const float*)d_in[2];
  const float* Wqkv  = (const float*)d_in[3];
  const float* Wproj = (const float*)d_in[4];
  const float* bproj = (const float*)d_in[5];
  const float* ln2g  = (const float*)d_in[6];
  const float* ln2b  = (const float*)d_in[7];
  const float* W1    = (const float*)d_in[8];
  const float* b1    = (const float*)d_in[9];
  const float* W2    = (const float*)d_in[10];
  const float* b2    = (const float*)d_in[11];
  float* out = (float*)d_out;

  unsigned char* base = (unsigned char*)d_ws;
  size_t off = 0;
  auto alloc = [&](size_t bytes) -> void* {
    off = (off + 255) & ~(size_t)255;
    void* p = base + off;
    off += bytes;
    return p;
  };
  // Transposed bf16 weights [N][K] (replace the old plain-cvt buffers; same size)
  unsigned short* WqkvT  = (unsigned short*)alloc((size_t)(3*CC)*CC*2);
  unsigned short* WprojT = (unsigned short*)alloc((size_t)CC*CC*2);
  unsigned short* W1T    = (unsigned short*)alloc((size_t)HIDN*CC*2);
  unsigned short* W2T    = (unsigned short*)alloc((size_t)CC*HIDN*2);
  float* q0   = (float*)alloc((size_t)BB*CC*4);
  float* wv   = (float*)alloc((size_t)BB*CC*4);
  float* sc   = (float*)alloc((size_t)BB*NPATCH*4);
  int*   tok  = (int*)alloc((size_t)BB*NP*4);
  unsigned short* hbuf = (unsigned short*)alloc((size_t)MR*CC*2);   // ln1-out, then attn-out, then ln2-out
  float* xk   = (float*)alloc((size_t)MR*CC*4);                     // dead after proj-GEMM
  unsigned short* qkv2 = (unsigned short*)alloc((size_t)MR*3*CC*2); // dead after attention
  if (off > ws_size) return;  // clean fail (no fault) if workspace too small

  unsigned short* obuf = hbuf;                 // alias: ln1-out dead when attn writes
  unsigned short* mid  = (unsigned short*)xk;  // alias: xk+qkv2 region (174 MB >= 139.2 MB)
  float* x2 = out;                             // residual stream 2 lives in d_out

  // weights: fused transpose + cvt  (in [K][N] f32 -> out [N][K] bf16)
  tcvt_kernel<<<dim3((3*CC)/64, CC/64), 256, 0, stream>>>(Wqkv,  WqkvT,  CC, 3*CC);
  tcvt_kernel<<<dim3(CC/64, CC/64),     256, 0, stream>>>(Wproj, WprojT, CC, CC);
  tcvt_kernel<<<dim3(HIDN/64, CC/64),   256, 0, stream>>>(W1,    W1T,    CC, HIDN);
  tcvt_kernel<<<dim3(CC/64, HIDN/64),   256, 0, stream>>>(W2,    W2T,    HIDN, CC);

  // scoring + selection + gather
  q0_kernel<<<BB, 256, 0, stream>>>(x, Wqkv, q0);
  wvec_kernel<<<BB, 256, 0, stream>>>(Wqkv, q0, wv);
  score_kernel<<<dim3(NPATCH, BB), 64, 0, stream>>>(x, wv, sc);
  select_kernel<<<BB, 256, 0, stream>>>(sc, tok);
  gather_kernel<<<dim3(NP, BB), 256, 0, stream>>>(x, tok, xk);

  // attention block
  ln_kernel<<<MR, 256, 0, stream>>>(xk, ln1g, ln1b, hbuf);
  gemm128<0><<<(MR/128)*((3*CC)/128), 256, 0, stream>>>(hbuf, WqkvT, nullptr, nullptr, qkv2, MR, 3*CC, CC);
  attn_kernel<<<dim3(3, HH, BB), 256, 0, stream>>>(qkv2, obuf);
  gemm128<1><<<(MR/128)*(CC/128), 256, 0, stream>>>(obuf, WprojT, bproj, xk, x2, MR, CC, CC);

  // MLP block
  ln_kernel<<<MR, 256, 0, stream>>>(x2, ln2g, ln2b, hbuf);
  gemm128<2><<<(MR/128)*(HIDN/128), 256, 0, stream>>>(hbuf, W1T, b1, nullptr, mid, MR, HIDN, CC);
  gemm128<3><<<(MR/128)*(CC/128), 256, 0, stream>>>(mid, W2T, b2, x2, out, MR, CC, HIDN);
}

// Round 4
// 846.033 us; speedup vs baseline: 2.2066x; 1.2222x over previous
//
#include <hip/hip_runtime.h>
#include <math.h>

#define BB 128
#define NTOK 197
#define CC 768
#define HH 12
#define HD 64
#define HIDN 3072
#define NP 177
#define NPATCH 196
#define THRK 19
#define MR (BB*NP)   // 22656 rows = 177*128

using short8 = __attribute__((ext_vector_type(8))) short;
using f32x4  = __attribute__((ext_vector_type(4))) float;

__device__ __forceinline__ unsigned short f2b(float f){
  unsigned u = __builtin_bit_cast(unsigned, f);
  u += 0x7fffu + ((u >> 16) & 1u);
  return (unsigned short)(u >> 16);
}

__device__ __forceinline__ void gload16(const void* src, void* lds){
  __builtin_amdgcn_global_load_lds(
      (const __attribute__((address_space(1))) unsigned int*)src,
      (__attribute__((address_space(3))) unsigned int*)lds,
      16, 0, 0);
}

// ---------- fused transpose+cvt: W[K][N] f32 -> Wt[N][K] bf16 ----------
__global__ void tcvt_kernel(const float* __restrict__ in, unsigned short* __restrict__ out, int K, int N){
  __shared__ float tile[64][65];
  int n0 = blockIdx.x*64, k0 = blockIdx.y*64;
  int t = threadIdx.x;
  int r = t >> 6, c = t & 63;
  #pragma unroll
  for (int i = 0; i < 16; ++i)
    tile[r + i*4][c] = in[(size_t)(k0 + r + i*4)*N + n0 + c];
  __syncthreads();
  #pragma unroll
  for (int i = 0; i < 16; ++i)
    out[(size_t)(n0 + r + i*4)*K + k0 + c] = f2b(tile[c][r + i*4]);
}

// ---------- scoring path (fp64 accum: selection boundary must not flip) ----------
__global__ void q0_kernel(const float* __restrict__ x, const float* __restrict__ Wqkv, float* __restrict__ q0){
  int b = blockIdx.x, t = threadIdx.x;
  int c = blockIdx.y*256 + t;
  __shared__ float xs[CC];
  for (int j = t; j < CC; j += 256) xs[j] = x[(size_t)b*NTOK*CC + j];
  __syncthreads();
  double acc = 0.0;
  for (int j = 0; j < CC; ++j) acc = fma((double)xs[j], (double)Wqkv[(size_t)j*(3*CC) + c], acc);
  q0[b*CC + c] = (float)acc;
}

__global__ void wvec_kernel(const float* __restrict__ Wqkv, const float* __restrict__ q0, float* __restrict__ wv){
  int b = blockIdx.x, t = threadIdx.x;
  int j = blockIdx.y*256 + t;
  __shared__ float qs[CC];
  for (int c = t; c < CC; c += 256) qs[c] = q0[b*CC + c];
  __syncthreads();
  const float* row = Wqkv + (size_t)j*(3*CC) + CC;  // Wk column block
  double acc = 0.0;
  for (int c = 0; c < CC; ++c) acc = fma((double)row[c], (double)qs[c], acc);
  wv[b*CC + j] = (float)acc;
}

__global__ void score_kernel(const float* __restrict__ x, const float* __restrict__ wv, float* __restrict__ sc){
  int m = blockIdx.x, b = blockIdx.y, l = threadIdx.x;  // one wave per (b,m)
  const float* xr = x + ((size_t)b*NTOK + 1 + m)*CC;
  const float* wr = wv + b*CC;
  double acc = 0.0;
  for (int c = l; c < CC; c += 64) acc = fma((double)xr[c], (double)wr[c], acc);
  for (int off = 32; off; off >>= 1) acc += __shfl_down(acc, off);
  if (l == 0) sc[b*NPATCH + m] = (float)(acc * (1.0/12.0));
}

// stable rank (== argsort(argsort) with stable ties), keep rank>19, compact in order
__global__ void select_kernel(const float* __restrict__ sc, int* __restrict__ tok){
  int b = blockIdx.x, t = threadIdx.x;
  __shared__ float s[NPATCH];
  __shared__ int kp[NPATCH];
  for (int m = t; m < NPATCH; m += 256) s[m] = sc[b*NPATCH + m];
  __syncthreads();
  for (int m = t; m < NPATCH; m += 256){
    float v = s[m]; int rank = 0;
    for (int j = 0; j < NPATCH; ++j){
      float u = s[j];
      rank += (u < v) || (u == v && j < m);
    }
    kp[m] = (rank > THRK) ? 1 : 0;
  }
  __syncthreads();
  for (int m = t; m < NPATCH; m += 256){
    if (kp[m]){
      int pos = 0;
      for (int j = 0; j < m; ++j) pos += kp[j];
      tok[b*NP + 1 + pos] = m + 1;
    }
  }
  if (t == 0) tok[b*NP] = 0;
}

__global__ void gather_kernel(const float* __restrict__ x, const int* __restrict__ tok, float* __restrict__ xk){
  int i = blockIdx.x, b = blockIdx.y, t = threadIdx.x;
  int src = tok[b*NP + i];
  const float* xr = x + ((size_t)b*NTOK + src)*CC;
  float* o = xk + ((size_t)b*NP + i)*CC;
  for (int c = t; c < CC; c += 256) o[c] = xr[c] * (1.0f/0.9f);
}

// ---------- LayerNorm: fp32 in -> bf16 out ----------
__global__ void ln_kernel(const float* __restrict__ in, const float* __restrict__ g,
                          const float* __restrict__ bt, unsigned short* __restrict__ out){
  int row = blockIdx.x, t = threadIdx.x;
  const float* xr = in + (size_t)row*CC;
  float v0 = xr[t], v1 = xr[t+256], v2 = xr[t+512];
  float s = v0+v1+v2, ss = v0*v0+v1*v1+v2*v2;
  for (int off = 32; off; off >>= 1){ s += __shfl_down(s, off); ss += __shfl_down(ss, off); }
  __shared__ float red[8];
  int wid = t >> 6, lane = t & 63;
  if (lane == 0){ red[wid] = s; red[4+wid] = ss; }
  __syncthreads();
  if (t == 0){
    float S = red[0]+red[1]+red[2]+red[3], SS = red[4]+red[5]+red[6]+red[7];
    float mean = S * (1.0f/CC);
    float var = SS * (1.0f/CC) - mean*mean;
    red[0] = mean; red[1] = rsqrtf(var + 1e-5f);
  }
  __syncthreads();
  float mean = red[0], rstd = red[1];
  unsigned short* orow = out + (size_t)row*CC;
  orow[t]     = f2b((v0-mean)*rstd*g[t]     + bt[t]);
  orow[t+256] = f2b((v1-mean)*rstd*g[t+256] + bt[t+256]);
  orow[t+512] = f2b((v2-mean)*rstd*g[t+512] + bt[t+512]);
}

// ---------- GEMM: 128x128 tile, BK=32, double-buffered global_load_lds (T3 2-phase) ----------
// A [M][K] bf16 row-major, Bt [N][K] bf16 row-major. M%128==0, N%128==0, K%32==0.
// EPI: 0 = plain -> bf16 ; 1/3 = +bias +res -> f32 ; 2 = +bias, gelu -> bf16
template<int EPI>
__global__ __launch_bounds__(256) void gemm128(
    const unsigned short* __restrict__ A, const unsigned short* __restrict__ Bt,
    const float* __restrict__ bias, const float* __restrict__ res, void* __restrict__ outp,
    int M, int N, int K)
{
  __shared__ __align__(16) short As[2][128*32];
  __shared__ __align__(16) short Bs[2][128*32];
  // bijective XCD swizzle (m204): consecutive seq within an XCD chunk share the A-panel
  int nwg = gridDim.x, o = blockIdx.x;
  int q = nwg >> 3, rr = nwg & 7;
  int xcd = o & 7, seq = o >> 3;
  int wg = (xcd < rr) ? xcd*(q+1) + seq : rr*(q+1) + (xcd - rr)*q + seq;
  int nx = N >> 7;
  int m0 = (wg / nx) << 7, n0 = (wg % nx) << 7;

  int t = threadIdx.x, w = t >> 6, l = t & 63;
  int wr = w >> 1, wc = w & 1;
  // staging: lane l covers row +(l>>2), k-chunk (l&3)*8 within a 16-row wave slab
  int srow = w*16 + (l >> 2);
  int sk8  = (l & 3)*8;
  const unsigned short* Abase = A  + (size_t)(m0 + srow)*K + sk8;
  const unsigned short* Bbase = Bt + (size_t)(n0 + srow)*K + sk8;
  f32x4 acc[4][4] = {};

  int nt = K >> 5;
  // prologue: stage tile 0 into buf 0
  #pragma unroll
  for (int j = 0; j < 2; ++j){
    gload16(Abase + (size_t)(j*64)*K, &As[0][(j*64 + w*16)*32]);
    gload16(Bbase + (size_t)(j*64)*K, &Bs[0][(j*64 + w*16)*32]);
  }
  __syncthreads();   // drains vmcnt(0), publishes buf0

  int cur = 0;
  for (int ti = 0; ti < nt; ++ti){
    // issue next-tile loads into buf[cur^1] BEFORE compute (T3: drain happens after MFMA)
    if (ti + 1 < nt){
      int kt = (ti + 1) << 5;
      #pragma unroll
      for (int j = 0; j < 2; ++j){
        gload16(Abase + (size_t)(j*64)*K + kt, &As[cur^1][(j*64 + w*16)*32]);
        gload16(Bbase + (size_t)(j*64)*K + kt, &Bs[cur^1][(j*64 + w*16)*32]);
      }
    }
    short8 af[4], bf[4];
    #pragma unroll
    for (int i = 0; i < 4; ++i){
      af[i] = *reinterpret_cast<const short8*>(&As[cur][(wr*64 + i*16 + (l&15))*32 + (l>>4)*8]);
      bf[i] = *reinterpret_cast<const short8*>(&Bs[cur][(wc*64 + i*16 + (l&15))*32 + (l>>4)*8]);
    }
    #pragma unroll
    for (int i = 0; i < 4; ++i)
      #pragma unroll
      for (int jn = 0; jn < 4; ++jn)
        acc[i][jn] = __builtin_amdgcn_mfma_f32_16x16x32_bf16(af[i], bf[jn], acc[i][jn], 0, 0, 0);
    __syncthreads();   // single vmcnt(0)+barrier per K-step, after the MFMA cluster
    cur ^= 1;
  }

  #pragma unroll
  for (int i = 0; i < 4; ++i)
  #pragma unroll
  for (int jn = 0; jn < 4; ++jn){
    int row = m0 + wr*64 + i*16 + (l>>4)*4;
    int col = n0 + wc*64 + jn*16 + (l&15);
    #pragma unroll
    for (int r = 0; r < 4; ++r){
      float v = acc[i][jn][r];
      if (EPI != 0) v += bias[col];
      if (EPI == 2) v = 0.5f*v*(1.0f + erff(v*0.70710678118f));
      if (EPI == 1 || EPI == 3) v += res[(size_t)(row+r)*N + col];
      if (EPI == 0 || EPI == 2) ((unsigned short*)outp)[(size_t)(row+r)*N + col] = f2b(v);
      else                      ((float*)outp)[(size_t)(row+r)*N + col] = v;
    }
  }
}

// ---------- fused attention: QK^T -> softmax -> PV, per (rowblock, head, batch) ----------
__global__ __launch_bounds__(256) void attn_kernel(const unsigned short* __restrict__ qkv2,
                                                   unsigned short* __restrict__ o)
{
  int rt = blockIdx.x, h = blockIdx.y, b = blockIdx.z;
  int t = threadIdx.x, w = t >> 6, l = t & 63;
  __shared__ short Vt[64*192];       // Vt[d][m], m padded to 192
  __shared__ short P[4][16*192];     // per-wave P strip
  for (int idx = t; idx < NP*8; idx += 256){
    int m = idx >> 3, d0 = (idx & 7)*8;
    short8 v = *reinterpret_cast<const short8*>(qkv2 + (size_t)(b*NP+m)*(3*CC) + 2*CC + h*HD + d0);
    #pragma unroll
    for (int j = 0; j < 8; ++j) Vt[(d0+j)*192 + m] = v[j];
  }
  for (int idx = t; idx < 64*15; idx += 256){
    int d = idx/15, m = NP + idx%15;
    Vt[d*192 + m] = 0;
  }
  __syncthreads();
  int nb = rt*64 + w*16;
  int g = l >> 4, c = l & 15;
  int nq = nb + c; if (nq > NP-1) nq = NP-1;
  const unsigned short* qrow = qkv2 + (size_t)(b*NP+nq)*(3*CC) + h*HD + 8*g;
  short8 aq0 = *reinterpret_cast<const short8*>(qrow);
  short8 aq1 = *reinterpret_cast<const short8*>(qrow + 32);
  f32x4 acc[12];
  #pragma unroll
  for (int ct = 0; ct < 12; ++ct){
    int m = ct*16 + c; if (m > NP-1) m = NP-1;
    const unsigned short* krow = qkv2 + (size_t)(b*NP+m)*(3*CC) + CC + h*HD + 8*g;
    short8 bk0 = *reinterpret_cast<const short8*>(krow);
    short8 bk1 = *reinterpret_cast<const short8*>(krow + 32);
    f32x4 a = {};
    a = __builtin_amdgcn_mfma_f32_16x16x32_bf16(aq0, bk0, a, 0, 0, 0);
    a = __builtin_amdgcn_mfma_f32_16x16x32_bf16(aq1, bk1, a, 0, 0, 0);
    acc[ct] = a;
  }
  float mx[4] = {-INFINITY, -INFINITY, -INFINITY, -INFINITY};
  #pragma unroll
  for (int ct = 0; ct < 12; ++ct){
    bool valid = (ct*16 + c) < NP;
    #pragma unroll
    for (int r = 0; r < 4; ++r){
      float v = valid ? acc[ct][r]*0.125f : -INFINITY;
      acc[ct][r] = v;
      mx[r] = fmaxf(mx[r], v);
    }
  }
  #pragma unroll
  for (int off = 1; off < 16; off <<= 1){
    #pragma unroll
    for (int r = 0; r < 4; ++r) mx[r] = fmaxf(mx[r], __shfl_xor(mx[r], off));
  }
  float sm[4] = {0.f, 0.f, 0.f, 0.f};
  #pragma unroll
  for (int ct = 0; ct < 12; ++ct)
    #pragma unroll
    for (int r = 0; r < 4; ++r){
      float e = __expf(acc[ct][r] - mx[r]);
      acc[ct][r] = e; sm[r] += e;
    }
  #pragma unroll
  for (int off = 1; off < 16; off <<= 1){
    #pragma unroll
    for (int r = 0; r < 4; ++r) sm[r] += __shfl_xor(sm[r], off);
  }
  float inv[4];
  #pragma unroll
  for (int r = 0; r < 4; ++r) inv[r] = 1.0f / sm[r];
  #pragma unroll
  for (int ct = 0; ct < 12; ++ct)
    #pragma unroll
    for (int r = 0; r < 4; ++r)
      P[w][(4*g + r)*192 + ct*16 + c] = (short)f2b(acc[ct][r]*inv[r]);
  f32x4 acc2[4] = {};
  #pragma unroll
  for (int ks = 0; ks < 6; ++ks){
    short8 pa = *reinterpret_cast<const short8*>(&P[w][c*192 + ks*32 + 8*g]);
    #pragma unroll
    for (int ct2 = 0; ct2 < 4; ++ct2){
      short8 bv = *reinterpret_cast<const short8*>(&Vt[(ct2*16 + c)*192 + ks*32 + 8*g]);
      acc2[ct2] = __builtin_amdgcn_mfma_f32_16x16x32_bf16(pa, bv, acc2[ct2], 0, 0, 0);
    }
  }
  #pragma unroll
  for (int ct2 = 0; ct2 < 4; ++ct2){
    #pragma unroll
    for (int r = 0; r < 4; ++r){
      int n = nb + 4*g + r;
      if (n < NP) o[(size_t)(b*NP+n)*CC + h*HD + ct2*16 + c] = f2b(acc2[ct2][r]);
    }
  }
}

extern "C" void kernel_launch(void* const* d_in, const int* in_sizes, int n_in,
                              void* d_out, int out_size, void* d_ws, size_t ws_size,
                              hipStream_t stream) {
  const float* x     = (const float*)d_in[0];
  const float* ln1g  = (const float*)d_in[1];
  const float* ln1b  = (const float*)d_in[2];
  const float* Wqkv  = (const float*)d_in[3];
  const float* Wproj = (const float*)d_in[4];
  const float* bproj = (const float*)d_in[5];
  const float* ln2g  = (const float*)d_in[6];
  const float* ln2b  = (const float*)d_in[7];
  const float* W1    = (const float*)d_in[8];
  const float* b1    = (const float*)d_in[9];
  const float* W2    = (const float*)d_in[10];
  const float* b2    = (const float*)d_in[11];
  float* out = (float*)d_out;

  unsigned char* base = (unsigned char*)d_ws;
  size_t off = 0;
  auto alloc = [&](size_t bytes) -> void* {
    off = (off + 255) & ~(size_t)255;
    void* p = base + off;
    off += bytes;
    return p;
  };
  // Transposed bf16 weights [N][K]
  unsigned short* WqkvT  = (unsigned short*)alloc((size_t)(3*CC)*CC*2);
  unsigned short* WprojT = (unsigned short*)alloc((size_t)CC*CC*2);
  unsigned short* W1T    = (unsigned short*)alloc((size_t)HIDN*CC*2);
  unsigned short* W2T    = (unsigned short*)alloc((size_t)CC*HIDN*2);
  float* q0   = (float*)alloc((size_t)BB*CC*4);
  float* wv   = (float*)alloc((size_t)BB*CC*4);
  float* sc   = (float*)alloc((size_t)BB*NPATCH*4);
  int*   tok  = (int*)alloc((size_t)BB*NP*4);
  unsigned short* hbuf = (unsigned short*)alloc((size_t)MR*CC*2);   // ln1-out, then attn-out, then ln2-out
  float* xk   = (float*)alloc((size_t)MR*CC*4);                     // dead after proj-GEMM
  unsigned short* qkv2 = (unsigned short*)alloc((size_t)MR*3*CC*2); // dead after attention
  if (off > ws_size) return;  // clean fail (no fault) if workspace too small

  unsigned short* obuf = hbuf;                 // alias: ln1-out dead when attn writes
  unsigned short* mid  = (unsigned short*)xk;  // alias: xk+qkv2 region (174 MB >= 139.2 MB)
  float* x2 = out;                             // residual stream 2 lives in d_out

  // weights: fused transpose + cvt  (in [K][N] f32 -> out [N][K] bf16)
  tcvt_kernel<<<dim3((3*CC)/64, CC/64), 256, 0, stream>>>(Wqkv,  WqkvT,  CC, 3*CC);
  tcvt_kernel<<<dim3(CC/64, CC/64),     256, 0, stream>>>(Wproj, WprojT, CC, CC);
  tcvt_kernel<<<dim3(HIDN/64, CC/64),   256, 0, stream>>>(W1,    W1T,    CC, HIDN);
  tcvt_kernel<<<dim3(CC/64, HIDN/64),   256, 0, stream>>>(W2,    W2T,    HIDN, CC);

  // scoring + selection + gather
  q0_kernel<<<dim3(BB, 3), 256, 0, stream>>>(x, Wqkv, q0);
  wvec_kernel<<<dim3(BB, 3), 256, 0, stream>>>(Wqkv, q0, wv);
  score_kernel<<<dim3(NPATCH, BB), 64, 0, stream>>>(x, wv, sc);
  select_kernel<<<BB, 256, 0, stream>>>(sc, tok);
  gather_kernel<<<dim3(NP, BB), 256, 0, stream>>>(x, tok, xk);

  // attention block
  ln_kernel<<<MR, 256, 0, stream>>>(xk, ln1g, ln1b, hbuf);
  gemm128<0><<<(MR/128)*((3*CC)/128), 256, 0, stream>>>(hbuf, WqkvT, nullptr, nullptr, qkv2, MR, 3*CC, CC);
  attn_kernel<<<dim3(3, HH, BB), 256, 0, stream>>>(qkv2, obuf);
  gemm128<1><<<(MR/128)*(CC/128), 256, 0, stream>>>(obuf, WprojT, bproj, xk, x2, MR, CC, CC);

  // MLP block
  ln_kernel<<<MR, 256, 0, stream>>>(x2, ln2g, ln2b, hbuf);
  gemm128<2><<<(MR/128)*(HIDN/128), 256, 0, stream>>>(hbuf, W1T, b1, nullptr, mid, MR, HIDN, CC);
  gemm128<3><<<(MR/128)*(CC/128), 256, 0, stream>>>(mid, W2T, b2, x2, out, MR, CC, HIDN);
}